// Round 2
// baseline (119.439 us; speedup 1.0000x reference)
//
#include <hip/hip_runtime.h>

#define NNODES 1024
#define NHEADS 8
#define NHID 16
#define DIM 128            // NHEADS * NHID
#define NEG_SLOPE 0.2f
#define RPB 4              // rows (nodes i) per block
#define BLK 512            // threads: 8 heads x 64 j-slots
#define NJS 64             // j-slots
#define NJJ (NNODES / NJS) // 16 j-iterations per thread
#define RSTRIDE 132        // padded row stride (words) for reduction buffer; 132*4=528=16*33 (keeps 16B align)

// K0: exps[i][j] = adj[i][j] ? exp(s[i][j]) : 0   (0 encodes the mask; |s|<6 so no underflow)
__global__ __launch_bounds__(256) void prep_kernel(
    const int* __restrict__ adj, const float* __restrict__ s, float* __restrict__ exps)
{
    const int idx = blockIdx.x * 256 + threadIdx.x;   // over NNODES*NNODES/4
    const int4   a  = ((const int4*)adj)[idx];
    const float4 sv = ((const float4*)s)[idx];
    float4 r;
    r.x = a.x ? __expf(sv.x) : 0.f;
    r.y = a.y ? __expf(sv.y) : 0.f;
    r.z = a.z ? __expf(sv.z) : 0.f;
    r.w = a.w ? __expf(sv.w) : 0.f;
    ((float4*)exps)[idx] = r;
}

// K1: g = h @ W^T ; src[i,h] = g[i,h,:]·a_src ; dst[i,h] = g[i,h,:]·a_dst
__global__ __launch_bounds__(128) void proj_kernel(
    const float* __restrict__ h, const float* __restrict__ W,
    const float* __restrict__ attn_w,
    float* __restrict__ g, float* __restrict__ srcv, float* __restrict__ dstv)
{
    const int i = blockIdx.x;
    const int o = threadIdx.x;
    __shared__ float hs[DIM];
    hs[o] = h[(size_t)i * DIM + o];
    __syncthreads();
    const float4* hv = (const float4*)hs;
    const float4* wv = (const float4*)(W + (size_t)o * DIM);
    float acc = 0.f;
#pragma unroll
    for (int k = 0; k < DIM / 4; k++) {
        float4 a = hv[k]; float4 b = wv[k];
        acc = fmaf(a.x, b.x, fmaf(a.y, b.y, fmaf(a.z, b.z, fmaf(a.w, b.w, acc))));
    }
    g[(size_t)i * DIM + o] = acc;
    const int f  = o & (NHID - 1);
    const int hd = o >> 4;
    float sv = acc * attn_w[f];
    float dv = acc * attn_w[NHID + f];
#pragma unroll
    for (int off = 8; off > 0; off >>= 1) {
        sv += __shfl_xor(sv, off, 64);
        dv += __shfl_xor(dv, off, 64);
    }
    if (f == 0) { srcv[i * NHEADS + hd] = sv; dstv[i * NHEADS + hd] = dv; }
}

// K2: RPB rows per block. Thread (h, js) computes its own weights (no LDS in inner loop),
// loads g[j][h][:] once, FMAs into acc[RPB][16] registers. Two-stage LDS tree at the end.
__global__ __launch_bounds__(BLK, 2) void attn_kernel(
    const float* __restrict__ exps, const float* __restrict__ g,
    const float* __restrict__ srcv, const float* __restrict__ dstv,
    float* __restrict__ out)
{
    const int i0   = blockIdx.x * RPB;
    const int tid  = threadIdx.x;
    const int h    = tid & 7;
    const int js   = tid >> 3;        // 0..63
    const int lane = tid & 63;
    const int wv   = tid >> 6;        // wave id 0..7

    __shared__ float sh_src[RPB * NHEADS];
    __shared__ float zeA[8][NHEADS][RPB];
    __shared__ float zsA[8][RPB];
    __shared__ float stat_e[NHEADS][RPB];
    __shared__ float stat_s[RPB];
    __shared__ float ztA[8][NHEADS][RPB];
    __shared__ float red[NJS * RSTRIDE];   // ~33 KB
    __shared__ float part[4][DIM];

    if (tid < RPB * NHEADS) sh_src[tid] = srcv[i0 * NHEADS + tid];
    __syncthreads();
    float sH[RPB];
#pragma unroll
    for (int r = 0; r < RPB; r++) sH[r] = sh_src[r * NHEADS + h];

    const float* erow0 = exps + (size_t)i0 * NNODES;

    // ---- Phase A: softmax denominators (e-channel per head, s-channel) ----
    float ze[RPB], zs[RPB];
#pragma unroll
    for (int r = 0; r < RPB; r++) { ze[r] = 0.f; zs[r] = 0.f; }
#pragma unroll 2
    for (int jj = 0; jj < NJJ; jj++) {
        const int j = jj * NJS + js;
        const float d = dstv[j * NHEADS + h];
#pragma unroll
        for (int r = 0; r < RPB; r++) {
            const float ev = erow0[r * NNODES + j];
            if (ev != 0.f) {
                float e = sH[r] + d;
                e = e > 0.f ? e : NEG_SLOPE * e;
                ze[r] += __expf(e);
                zs[r] += ev;            // all 8 h-lanes duplicate; fixed by *0.125 later
            }
        }
    }
#pragma unroll
    for (int off = 1; off <= 4; off <<= 1)
#pragma unroll
        for (int r = 0; r < RPB; r++) zs[r] += __shfl_xor(zs[r], off, 64);
#pragma unroll
    for (int off = 8; off <= 32; off <<= 1)
#pragma unroll
        for (int r = 0; r < RPB; r++) {
            ze[r] += __shfl_xor(ze[r], off, 64);
            zs[r] += __shfl_xor(zs[r], off, 64);
        }
    if (lane < NHEADS)                  // lane == h for js-in-wave == 0
#pragma unroll
        for (int r = 0; r < RPB; r++) zeA[wv][lane][r] = ze[r];
    if (lane == 0)
#pragma unroll
        for (int r = 0; r < RPB; r++) zsA[wv][r] = zs[r];
    __syncthreads();
    if (tid < NHEADS * RPB) {
        const int hh = tid & 7, rr = tid >> 3;
        float t = 0.f;
#pragma unroll
        for (int w = 0; w < 8; w++) t += zeA[w][hh][rr];
        stat_e[hh][rr] = 1.f / t;
    }
    if (tid >= 64 && tid < 64 + RPB) {
        const int rr = tid - 64;
        float t = 0.f;
#pragma unroll
        for (int w = 0; w < 8; w++) t += zsA[w][rr];
        stat_s[rr] = 1.f / (t * 0.125f);
    }
    __syncthreads();
    float ize[RPB], izs[RPB];
#pragma unroll
    for (int r = 0; r < RPB; r++) { ize[r] = stat_e[h][r]; izs[r] = stat_s[r]; }

    // ---- Phase B: final weights + register aggregation ----
    float acc[RPB][16];
#pragma unroll
    for (int r = 0; r < RPB; r++)
#pragma unroll
        for (int f = 0; f < 16; f++) acc[r][f] = 0.f;
    float zt[RPB];
#pragma unroll
    for (int r = 0; r < RPB; r++) zt[r] = 0.f;

#pragma unroll 2
    for (int jj = 0; jj < NJJ; jj++) {
        const int j = jj * NJS + js;
        const float d = dstv[j * NHEADS + h];
        const float4* gj = (const float4*)(g + (size_t)j * DIM + h * NHID);
        const float4 g0 = gj[0], g1 = gj[1], g2 = gj[2], g3 = gj[3];
#pragma unroll
        for (int r = 0; r < RPB; r++) {
            const float ev = erow0[r * NNODES + j];
            float w;
            if (ev != 0.f) {
                float e = sH[r] + d;
                e = e > 0.f ? e : NEG_SLOPE * e;
                const float aa = __expf(e) * ize[r];
                w = __expf(aa + ev * izs[r]);
            } else {
                w = 1.0f;               // exp(0) at masked positions
            }
            zt[r] += w;
            acc[r][0]  = fmaf(w, g0.x, acc[r][0]);
            acc[r][1]  = fmaf(w, g0.y, acc[r][1]);
            acc[r][2]  = fmaf(w, g0.z, acc[r][2]);
            acc[r][3]  = fmaf(w, g0.w, acc[r][3]);
            acc[r][4]  = fmaf(w, g1.x, acc[r][4]);
            acc[r][5]  = fmaf(w, g1.y, acc[r][5]);
            acc[r][6]  = fmaf(w, g1.z, acc[r][6]);
            acc[r][7]  = fmaf(w, g1.w, acc[r][7]);
            acc[r][8]  = fmaf(w, g2.x, acc[r][8]);
            acc[r][9]  = fmaf(w, g2.y, acc[r][9]);
            acc[r][10] = fmaf(w, g2.z, acc[r][10]);
            acc[r][11] = fmaf(w, g2.w, acc[r][11]);
            acc[r][12] = fmaf(w, g3.x, acc[r][12]);
            acc[r][13] = fmaf(w, g3.y, acc[r][13]);
            acc[r][14] = fmaf(w, g3.z, acc[r][14]);
            acc[r][15] = fmaf(w, g3.w, acc[r][15]);
        }
    }

    // zt: reduce over the 8 js-slots within the wave (lane bits 3,4,5); h-lanes stay distinct
#pragma unroll
    for (int off = 8; off <= 32; off <<= 1)
#pragma unroll
        for (int r = 0; r < RPB; r++) zt[r] += __shfl_xor(zt[r], off, 64);
    if (lane < NHEADS)
#pragma unroll
        for (int r = 0; r < RPB; r++) ztA[wv][lane][r] = zt[r];

    // ---- Epilogue: per-row two-stage LDS reduction over the 64 js-slots ----
    const int hf = tid & 127;
    const int ck = tid >> 7;           // 0..3
    const int oh = hf >> 4;
    float* myrow = red + js * RSTRIDE + h * NHID;
    for (int r = 0; r < RPB; r++) {
        __syncthreads();               // also covers ztA visibility on first iter
#pragma unroll
        for (int f = 0; f < 16; f++) myrow[f] = acc[r][f];
        __syncthreads();
        float p = 0.f;
#pragma unroll
        for (int k = 0; k < 16; k++) p += red[(ck * 16 + k) * RSTRIDE + hf];
        part[ck][hf] = p;
        __syncthreads();
        if (tid < DIM) {
            const float v = part[0][hf] + part[1][hf] + part[2][hf] + part[3][hf];
            float zq = 0.f;
#pragma unroll
            for (int w = 0; w < 8; w++) zq += ztA[w][oh][r];
            out[(size_t)(i0 + r) * DIM + hf] = v / zq;
        }
    }
}

extern "C" void kernel_launch(void* const* d_in, const int* in_sizes, int n_in,
                              void* d_out, int out_size, void* d_ws, size_t ws_size,
                              hipStream_t stream) {
    const float* h      = (const float*)d_in[0];
    const int*   adj    = (const int*)  d_in[1];
    const float* s      = (const float*)d_in[2];
    const float* W      = (const float*)d_in[3];
    const float* attn_w = (const float*)d_in[4];
    float* out  = (float*)d_out;
    float* g    = (float*)d_ws;                        // 1024*128
    float* srcv = g + (size_t)NNODES * DIM;            // 1024*8
    float* dstv = srcv + (size_t)NNODES * NHEADS;      // 1024*8
    float* exps = dstv + (size_t)NNODES * NHEADS;      // 1024*1024

    prep_kernel<<<(NNODES * NNODES / 4) / 256, 256, 0, stream>>>(adj, s, exps);
    proj_kernel<<<NNODES, DIM, 0, stream>>>(h, W, attn_w, g, srcv, dstv);
    attn_kernel<<<NNODES / RPB, BLK, 0, stream>>>(exps, g, srcv, dstv, out);
}

// Round 3
// 110.953 us; speedup vs baseline: 1.0765x; 1.0765x over previous
//
#include <hip/hip_runtime.h>

#define NNODES 1024
#define NHEADS 8
#define NHID 16
#define DIM 128            // NHEADS * NHID
#define NEG_SLOPE 0.2f
#define R 4                // rows per aggr block
#define JSPLIT 8           // j-splits per row group (128 j's per block)

// K1: g = h @ W^T ; src[i,h] = g[i,h,:]·a_src ; dst[i,h] = g[i,h,:]·a_dst
__global__ __launch_bounds__(128) void proj_kernel(
    const float* __restrict__ h, const float* __restrict__ W,
    const float* __restrict__ attn_w,
    float* __restrict__ g, float* __restrict__ srcv, float* __restrict__ dstv)
{
    const int i = blockIdx.x;
    const int o = threadIdx.x;
    __shared__ float hs[DIM];
    hs[o] = h[(size_t)i * DIM + o];
    __syncthreads();
    const float4* hv = (const float4*)hs;
    const float4* wv = (const float4*)(W + (size_t)o * DIM);
    float acc = 0.f;
#pragma unroll
    for (int k = 0; k < DIM / 4; k++) {
        float4 a = hv[k]; float4 b = wv[k];
        acc = fmaf(a.x, b.x, fmaf(a.y, b.y, fmaf(a.z, b.z, fmaf(a.w, b.w, acc))));
    }
    g[(size_t)i * DIM + o] = acc;
    const int f  = o & (NHID - 1);
    const int hd = o >> 4;
    float sv = acc * attn_w[f];
    float dv = acc * attn_w[NHID + f];
#pragma unroll
    for (int off = 8; off > 0; off >>= 1) {
        sv += __shfl_xor(sv, off, 64);
        dv += __shfl_xor(dv, off, 64);
    }
    if (f == 0) { srcv[i * NHEADS + hd] = sv; dstv[i * NHEADS + hd] = dv; }
}

// K2: one block per row i. exps[i][j] = adj ? exp(s) : 0 ; 1/ze per head ; 1/zs.
__global__ __launch_bounds__(256) void denom_kernel(
    const int* __restrict__ adj, const float* __restrict__ s,
    const float* __restrict__ srcv, const float* __restrict__ dstv,
    float* __restrict__ exps, float* __restrict__ statE, float* __restrict__ statS)
{
    const int i    = blockIdx.x;
    const int tid  = threadIdx.x;
    const int lane = tid & 63;
    const int wv   = tid >> 6;
    __shared__ float sh_src[NHEADS];
    __shared__ float redA[4][12];
    if (tid < NHEADS) sh_src[tid] = srcv[i * NHEADS + tid];
    __syncthreads();
    float sH[8];
#pragma unroll
    for (int hh = 0; hh < 8; hh++) sH[hh] = sh_src[hh];

    const int*   arow = adj + (size_t)i * NNODES;
    const float* srow = s   + (size_t)i * NNODES;
    float ze[8]; float zs = 0.f;
#pragma unroll
    for (int hh = 0; hh < 8; hh++) ze[hh] = 0.f;
#pragma unroll
    for (int jj = 0; jj < 4; jj++) {
        const int j = jj * 256 + tid;
        const int a = arow[j];
        const float ev = a ? __expf(srow[j]) : 0.f;
        exps[(size_t)i * NNODES + j] = ev;
        zs += ev;
        const float4* d4 = (const float4*)(dstv + j * NHEADS);
        const float4 d0 = d4[0], d1 = d4[1];
        const float dj[8] = {d0.x, d0.y, d0.z, d0.w, d1.x, d1.y, d1.z, d1.w};
#pragma unroll
        for (int hh = 0; hh < 8; hh++) {
            float e = sH[hh] + dj[hh];
            e = e > 0.f ? e : NEG_SLOPE * e;
            const float t = __expf(e);
            ze[hh] += a ? t : 0.f;
        }
    }
#pragma unroll
    for (int off = 1; off <= 32; off <<= 1) {
#pragma unroll
        for (int hh = 0; hh < 8; hh++) ze[hh] += __shfl_xor(ze[hh], off, 64);
        zs += __shfl_xor(zs, off, 64);
    }
    if (lane == 0) {
#pragma unroll
        for (int hh = 0; hh < 8; hh++) redA[wv][hh] = ze[hh];
        redA[wv][8] = zs;
    }
    __syncthreads();
    if (tid < 9) {
        const float t = redA[0][tid] + redA[1][tid] + redA[2][tid] + redA[3][tid];
        if (tid < 8) statE[i * NHEADS + tid] = 1.f / t;
        else         statS[i] = 1.f / t;
    }
}

// K3: block = (row-group rg of R rows) x (j-split of 128 j's). Thread (h, js32).
// Computes w privately, FMAs g into registers, writes per-block partials.
__global__ __launch_bounds__(256, 4) void aggr_kernel(
    const float* __restrict__ exps, const float* __restrict__ g,
    const float* __restrict__ srcv, const float* __restrict__ dstv,
    const float* __restrict__ statE, const float* __restrict__ statS,
    float* __restrict__ accp, float* __restrict__ ztp)
{
    const int rg    = blockIdx.x >> 3;
    const int jsp   = blockIdx.x & 7;
    const int i0    = rg * R;
    const int jbase = jsp * (NNODES / JSPLIT);
    const int tid   = threadIdx.x;
    const int h     = tid & 7;
    const int js32  = tid >> 3;       // 0..31
    const int lane  = tid & 63;
    const int wv    = tid >> 6;

    float sH[R], ize[R], izs[R];
#pragma unroll
    for (int r = 0; r < R; r++) {
        sH[r]  = srcv[(i0 + r) * NHEADS + h];
        ize[r] = statE[(i0 + r) * NHEADS + h];
        izs[r] = statS[i0 + r];
    }

    float acc[R][16];
#pragma unroll
    for (int r = 0; r < R; r++)
#pragma unroll
        for (int f = 0; f < 16; f++) acc[r][f] = 0.f;
    float zt[R];
#pragma unroll
    for (int r = 0; r < R; r++) zt[r] = 0.f;

#pragma unroll
    for (int jj = 0; jj < 4; jj++) {
        const int j = jbase + jj * 32 + js32;
        const float d = dstv[j * NHEADS + h];
        const float4* gj = (const float4*)(g + (size_t)j * DIM + h * NHID);
        const float4 g0 = gj[0], g1 = gj[1], g2 = gj[2], g3 = gj[3];
#pragma unroll
        for (int r = 0; r < R; r++) {
            const float ev = exps[(size_t)(i0 + r) * NNODES + j];
            float e = sH[r] + d;
            e = e > 0.f ? e : NEG_SLOPE * e;
            const float aa = __expf(e) * ize[r];
            const float w  = (ev != 0.f) ? __expf(aa + ev * izs[r]) : 1.0f;
            zt[r] += w;
            acc[r][0]  = fmaf(w, g0.x, acc[r][0]);
            acc[r][1]  = fmaf(w, g0.y, acc[r][1]);
            acc[r][2]  = fmaf(w, g0.z, acc[r][2]);
            acc[r][3]  = fmaf(w, g0.w, acc[r][3]);
            acc[r][4]  = fmaf(w, g1.x, acc[r][4]);
            acc[r][5]  = fmaf(w, g1.y, acc[r][5]);
            acc[r][6]  = fmaf(w, g1.z, acc[r][6]);
            acc[r][7]  = fmaf(w, g1.w, acc[r][7]);
            acc[r][8]  = fmaf(w, g2.x, acc[r][8]);
            acc[r][9]  = fmaf(w, g2.y, acc[r][9]);
            acc[r][10] = fmaf(w, g2.z, acc[r][10]);
            acc[r][11] = fmaf(w, g2.w, acc[r][11]);
            acc[r][12] = fmaf(w, g3.x, acc[r][12]);
            acc[r][13] = fmaf(w, g3.y, acc[r][13]);
            acc[r][14] = fmaf(w, g3.z, acc[r][14]);
            acc[r][15] = fmaf(w, g3.w, acc[r][15]);
        }
    }

    // zt: reduce over the 8 js-slots within the wave (lane bits 3..5)
#pragma unroll
    for (int off = 8; off <= 32; off <<= 1)
#pragma unroll
        for (int r = 0; r < R; r++) zt[r] += __shfl_xor(zt[r], off, 64);

    __shared__ float ztA[4][NHEADS][R];
    __shared__ float red[32 * 132];    // 16.9 KB, row stride 132 (16B-aligned, odd/32)
    __shared__ float part[2][DIM];
    if (lane < NHEADS)
#pragma unroll
        for (int r = 0; r < R; r++) ztA[wv][lane][r] = zt[r];

    float* myrow = red + js32 * 132 + h * NHID;
    const int hf   = tid & 127;
    const int half = tid >> 7;
    for (int r = 0; r < R; r++) {
        __syncthreads();
#pragma unroll
        for (int q = 0; q < 4; q++)
            ((float4*)myrow)[q] = make_float4(acc[r][4*q], acc[r][4*q+1],
                                              acc[r][4*q+2], acc[r][4*q+3]);
        __syncthreads();
        float p = 0.f;
#pragma unroll
        for (int k = 0; k < 16; k++) p += red[(half * 16 + k) * 132 + hf];
        part[half][hf] = p;
        __syncthreads();
        if (tid < DIM)
            accp[((size_t)jsp * NNODES + i0 + r) * DIM + hf] = part[0][hf] + part[1][hf];
    }
    if (tid < NHEADS * R) {
        const int hh = tid & 7, rr = tid >> 3;
        ztp[((size_t)jsp * NNODES + i0 + rr) * NHEADS + hh] =
            ztA[0][hh][rr] + ztA[1][hh][rr] + ztA[2][hh][rr] + ztA[3][hh][rr];
    }
}

// K4: combine partials, normalize.
__global__ __launch_bounds__(256) void finish_kernel(
    const float* __restrict__ accp, const float* __restrict__ ztp,
    float* __restrict__ out)
{
    const int idx = blockIdx.x * 256 + threadIdx.x;   // over 1024*128
    const int i  = idx >> 7;
    const int hf = idx & 127;
    const int oh = hf >> 4;
    float v = 0.f, z = 0.f;
#pragma unroll
    for (int js = 0; js < JSPLIT; js++) {
        v += accp[((size_t)js * NNODES + i) * DIM + hf];
        z += ztp[((size_t)js * NNODES + i) * NHEADS + oh];
    }
    out[idx] = v / z;
}

extern "C" void kernel_launch(void* const* d_in, const int* in_sizes, int n_in,
                              void* d_out, int out_size, void* d_ws, size_t ws_size,
                              hipStream_t stream) {
    const float* h      = (const float*)d_in[0];
    const int*   adj    = (const int*)  d_in[1];
    const float* s      = (const float*)d_in[2];
    const float* W      = (const float*)d_in[3];
    const float* attn_w = (const float*)d_in[4];
    float* out = (float*)d_out;

    float* g     = (float*)d_ws;                        // 1024*128
    float* srcv  = g     + (size_t)NNODES * DIM;        // 1024*8
    float* dstv  = srcv  + (size_t)NNODES * NHEADS;     // 1024*8
    float* exps  = dstv  + (size_t)NNODES * NHEADS;     // 1024*1024
    float* statE = exps  + (size_t)NNODES * NNODES;     // 1024*8
    float* statS = statE + (size_t)NNODES * NHEADS;     // 1024
    float* ztp   = statS + (size_t)NNODES;              // 8*1024*8
    float* accp  = ztp   + (size_t)JSPLIT * NNODES * NHEADS;  // 8*1024*128

    proj_kernel  <<<NNODES, DIM, 0, stream>>>(h, W, attn_w, g, srcv, dstv);
    denom_kernel <<<NNODES, 256, 0, stream>>>(adj, s, srcv, dstv, exps, statE, statS);
    aggr_kernel  <<<(NNODES / R) * JSPLIT, 256, 0, stream>>>(exps, g, srcv, dstv,
                                                             statE, statS, accp, ztp);
    finish_kernel<<<(NNODES * DIM) / 256, 256, 0, stream>>>(accp, ztp, out);
}

// Round 4
// 95.495 us; speedup vs baseline: 1.2507x; 1.1619x over previous
//
#include <hip/hip_runtime.h>

#define NNODES 1024
#define NHEADS 8
#define NHID 16
#define DIM 128            // NHEADS * NHID
#define NEG_SLOPE 0.2f

// K1: g = h @ W^T ; src[i,h] = g[i,h,:]·a_src ; dst[i,h] = g[i,h,:]·a_dst
__global__ __launch_bounds__(128) void proj_kernel(
    const float* __restrict__ h, const float* __restrict__ W,
    const float* __restrict__ attn_w,
    float* __restrict__ g, float* __restrict__ srcv, float* __restrict__ dstv)
{
    const int i = blockIdx.x;
    const int o = threadIdx.x;
    __shared__ float hs[DIM];
    hs[o] = h[(size_t)i * DIM + o];
    __syncthreads();
    const float4* hv = (const float4*)hs;
    const float4* wv = (const float4*)(W + (size_t)o * DIM);
    float acc = 0.f;
#pragma unroll
    for (int k = 0; k < DIM / 4; k++) {
        float4 a = hv[k]; float4 b = wv[k];
        acc = fmaf(a.x, b.x, fmaf(a.y, b.y, fmaf(a.z, b.z, fmaf(a.w, b.w, acc))));
    }
    g[(size_t)i * DIM + o] = acc;
    const int f  = o & (NHID - 1);
    const int hd = o >> 4;
    float sv = acc * attn_w[f];
    float dv = acc * attn_w[NHID + f];
#pragma unroll
    for (int off = 8; off > 0; off >>= 1) {
        sv += __shfl_xor(sv, off, 64);
        dv += __shfl_xor(dv, off, 64);
    }
    if (f == 0) { srcv[i * NHEADS + hd] = sv; dstv[i * NHEADS + hd] = dv; }
}

// K2: one block per 2 rows. Everything in-block: ev row in LDS, denominators,
// register-private weights, register accumulation, shuffle-tree epilogue.
__global__ __launch_bounds__(256, 2) void fused_kernel(
    const int* __restrict__ adj, const float* __restrict__ s,
    const float* __restrict__ g, const float* __restrict__ srcv,
    const float* __restrict__ dstv, float* __restrict__ out)
{
    const int i0   = blockIdx.x * 2;
    const int tid  = threadIdx.x;
    const int h    = tid & 7;
    const int js   = tid >> 3;        // 0..31
    const int lane = tid & 63;
    const int wv   = tid >> 6;        // wave 0..3

    __shared__ float evL[2][NNODES];          // 8 KB: exp(s) or 0 per row
    __shared__ float zeA[4][NHEADS][2];
    __shared__ float zsA[4][2];
    __shared__ float statE[2][NHEADS];
    __shared__ float statS[2];
    __shared__ float redO[4][2][NHEADS][16];  // 4 KB
    __shared__ float ztA[4][2][NHEADS];

    // ---- Phase A1: ev = adj ? exp(s) : 0 into LDS; zs partial ----
    float zs[2] = {0.f, 0.f};
#pragma unroll
    for (int r = 0; r < 2; r++) {
        const int4   a  = ((const int4*)  adj)[(size_t)(i0 + r) * (NNODES/4) + tid];
        const float4 sv = ((const float4*)s  )[(size_t)(i0 + r) * (NNODES/4) + tid];
        float4 e4;
        e4.x = a.x ? __expf(sv.x) : 0.f;
        e4.y = a.y ? __expf(sv.y) : 0.f;
        e4.z = a.z ? __expf(sv.z) : 0.f;
        e4.w = a.w ? __expf(sv.w) : 0.f;
        ((float4*)evL[r])[tid] = e4;
        zs[r] += e4.x + e4.y + e4.z + e4.w;
    }
    const float sH[2] = { srcv[(size_t)i0 * NHEADS + h],
                          srcv[(size_t)(i0 + 1) * NHEADS + h] };
    __syncthreads();

    // ---- Phase A2: ze[r][h] = sum over unmasked j of exp(lrelu(src+dst)) ----
    float ze[2] = {0.f, 0.f};
#pragma unroll 4
    for (int t = 0; t < 32; t++) {
        const int j = t * 32 + js;
        const float d = dstv[j * NHEADS + h];
#pragma unroll
        for (int r = 0; r < 2; r++) {
            float e = sH[r] + d;
            e = e > 0.f ? e : NEG_SLOPE * e;
            const float x = __expf(e);
            ze[r] += (evL[r][j] != 0.f) ? x : 0.f;
        }
    }
#pragma unroll
    for (int off = 8; off <= 32; off <<= 1)
#pragma unroll
        for (int r = 0; r < 2; r++) ze[r] += __shfl_xor(ze[r], off, 64);
#pragma unroll
    for (int off = 1; off <= 32; off <<= 1)
#pragma unroll
        for (int r = 0; r < 2; r++) zs[r] += __shfl_xor(zs[r], off, 64);
    if (lane < NHEADS) { zeA[wv][lane][0] = ze[0]; zeA[wv][lane][1] = ze[1]; }
    if (lane == 0)     { zsA[wv][0] = zs[0]; zsA[wv][1] = zs[1]; }
    __syncthreads();
    if (tid < 16) {
        const int hh = tid & 7, rr = tid >> 3;
        statE[rr][hh] = 1.f / (zeA[0][hh][rr] + zeA[1][hh][rr] +
                               zeA[2][hh][rr] + zeA[3][hh][rr]);
    } else if (tid < 18) {
        const int rr = tid - 16;
        statS[rr] = 1.f / (zsA[0][rr] + zsA[1][rr] + zsA[2][rr] + zsA[3][rr]);
    }
    __syncthreads();
    const float ize[2] = { statE[0][h], statE[1][h] };
    const float izs[2] = { statS[0],    statS[1]    };

    // ---- Phase B: w private, FMA g rows into registers ----
    float acc[2][16];
#pragma unroll
    for (int r = 0; r < 2; r++)
#pragma unroll
        for (int f = 0; f < 16; f++) acc[r][f] = 0.f;
    float zt[2] = {0.f, 0.f};

#pragma unroll 2
    for (int t = 0; t < 32; t++) {
        const int j = t * 32 + js;
        const float d = dstv[j * NHEADS + h];
        const float4* gj = (const float4*)(g + (size_t)j * DIM + h * NHID);
        const float4 g0 = gj[0], g1 = gj[1], g2 = gj[2], g3 = gj[3];
#pragma unroll
        for (int r = 0; r < 2; r++) {
            const float ev = evL[r][j];
            float e = sH[r] + d;
            e = e > 0.f ? e : NEG_SLOPE * e;
            const float w = (ev != 0.f)
                ? __expf(__expf(e) * ize[r] + ev * izs[r])
                : 1.0f;               // exp(0) at masked positions
            zt[r] += w;
            acc[r][0]  = fmaf(w, g0.x, acc[r][0]);
            acc[r][1]  = fmaf(w, g0.y, acc[r][1]);
            acc[r][2]  = fmaf(w, g0.z, acc[r][2]);
            acc[r][3]  = fmaf(w, g0.w, acc[r][3]);
            acc[r][4]  = fmaf(w, g1.x, acc[r][4]);
            acc[r][5]  = fmaf(w, g1.y, acc[r][5]);
            acc[r][6]  = fmaf(w, g1.z, acc[r][6]);
            acc[r][7]  = fmaf(w, g1.w, acc[r][7]);
            acc[r][8]  = fmaf(w, g2.x, acc[r][8]);
            acc[r][9]  = fmaf(w, g2.y, acc[r][9]);
            acc[r][10] = fmaf(w, g2.z, acc[r][10]);
            acc[r][11] = fmaf(w, g2.w, acc[r][11]);
            acc[r][12] = fmaf(w, g3.x, acc[r][12]);
            acc[r][13] = fmaf(w, g3.y, acc[r][13]);
            acc[r][14] = fmaf(w, g3.z, acc[r][14]);
            acc[r][15] = fmaf(w, g3.w, acc[r][15]);
        }
    }

    // ---- Epilogue: reduce over js-in-wave (lane bits 3..5), then 4 waves ----
#pragma unroll
    for (int off = 8; off <= 32; off <<= 1)
#pragma unroll
        for (int r = 0; r < 2; r++) {
#pragma unroll
            for (int f = 0; f < 16; f++)
                acc[r][f] += __shfl_xor(acc[r][f], off, 64);
            zt[r] += __shfl_xor(zt[r], off, 64);
        }
    if (lane < NHEADS) {
#pragma unroll
        for (int r = 0; r < 2; r++) {
#pragma unroll
            for (int f = 0; f < 16; f++) redO[wv][r][lane][f] = acc[r][f];
            ztA[wv][r][lane] = zt[r];
        }
    }
    __syncthreads();
    {
        const int rr = tid >> 7;
        const int hf = tid & 127;
        const int oh = hf >> 4;
        const int f  = hf & 15;
        const float v  = redO[0][rr][oh][f] + redO[1][rr][oh][f] +
                         redO[2][rr][oh][f] + redO[3][rr][oh][f];
        const float zq = ztA[0][rr][oh] + ztA[1][rr][oh] +
                         ztA[2][rr][oh] + ztA[3][rr][oh];
        out[(size_t)(i0 + rr) * DIM + hf] = v / zq;
    }
}

extern "C" void kernel_launch(void* const* d_in, const int* in_sizes, int n_in,
                              void* d_out, int out_size, void* d_ws, size_t ws_size,
                              hipStream_t stream) {
    const float* h      = (const float*)d_in[0];
    const int*   adj    = (const int*)  d_in[1];
    const float* s      = (const float*)d_in[2];
    const float* W      = (const float*)d_in[3];
    const float* attn_w = (const float*)d_in[4];
    float* out = (float*)d_out;

    float* g    = (float*)d_ws;                      // 1024*128
    float* srcv = g    + (size_t)NNODES * DIM;       // 1024*8
    float* dstv = srcv + (size_t)NNODES * NHEADS;    // 1024*8

    proj_kernel <<<NNODES, DIM, 0, stream>>>(h, W, attn_w, g, srcv, dstv);
    fused_kernel<<<NNODES / 2, 256, 0, stream>>>(adj, s, g, srcv, dstv, out);
}